// Round 9
// baseline (109.200 us; speedup 1.0000x reference)
//
#include <hip/hip_runtime.h>
#include <hip/hip_bf16.h>

#define B_    8
#define N_    9225
#define M_    4096
#define K_    32
#define HID_  64
#define DOUT_ 16

typedef __attribute__((ext_vector_type(8))) short short8;
typedef __attribute__((ext_vector_type(4))) float floatx4;
typedef __attribute__((ext_vector_type(2))) float f32x2;

static __device__ __forceinline__ short f2bf(float f) {
    __hip_bfloat16 h = __float2bfloat16(f);
    return __builtin_bit_cast(short, h);
}
static __device__ __forceinline__ f32x2 splat2(float v) { return (f32x2){v, v}; }
static __device__ __forceinline__ int bpermi(int src_bytes, int v) {
    return __builtin_amdgcn_ds_bpermute(src_bytes, v);
}
static __device__ __forceinline__ float bpermf(int src_bytes, float v) {
    return __builtin_bit_cast(float,
        __builtin_amdgcn_ds_bpermute(src_bytes, __builtin_bit_cast(int, v)));
}

// Sum over each 16-lane DPP row via row_shr tree; lane (row*16+15) holds the sum.
static __device__ __forceinline__ float row16_sum(float v) {
    int t;
    t = __builtin_amdgcn_update_dpp(0, __builtin_bit_cast(int, v), 0x111, 0xF, 0xF, true);
    v += __builtin_bit_cast(float, t);
    t = __builtin_amdgcn_update_dpp(0, __builtin_bit_cast(int, v), 0x112, 0xF, 0xF, true);
    v += __builtin_bit_cast(float, t);
    t = __builtin_amdgcn_update_dpp(0, __builtin_bit_cast(int, v), 0x114, 0xF, 0xF, true);
    v += __builtin_bit_cast(float, t);
    t = __builtin_amdgcn_update_dpp(0, __builtin_bit_cast(int, v), 0x118, 0xF, 0xF, true);
    v += __builtin_bit_cast(float, t);
    return v;
}

// gelu(x) ~ 0.5*x*(1 + tanh(z)), z = x*(0.79788456 + 0.035677408*x^2),
// tanh via Pade(5,4), clamped to [-1,1]. No v_exp. (Validated R4/R5/R8.)
static __device__ __forceinline__ f32x2 gelu2(f32x2 x) {
    const f32x2 xsq = x * x;
    const f32x2 t   = __builtin_elementwise_fma(xsq, splat2(0.035677408f), splat2(0.79788456f));
    const f32x2 z   = x * t;
    const f32x2 u   = z * z;
    const f32x2 a   = u + splat2(105.0f);
    const f32x2 nin = __builtin_elementwise_fma(u, a, splat2(945.0f));
    const f32x2 num = z * nin;
    const f32x2 bq  = __builtin_elementwise_fma(u, splat2(15.0f), splat2(420.0f));
    const f32x2 den = __builtin_elementwise_fma(u, bq, splat2(945.0f));
    const f32x2 r   = { __builtin_amdgcn_rcpf(den[0]), __builtin_amdgcn_rcpf(den[1]) };
    f32x2 th = num * r;
    th = __builtin_elementwise_min(__builtin_elementwise_max(th, splat2(-1.0f)), splat2(1.0f));
    const f32x2 hx = x * splat2(0.5f);
    return __builtin_elementwise_fma(hx, th, hx);
}

// Wave owns 2 rows (R5/R8 structure). Register-diet revision: target VGPR<=64
// (the 8-waves/SIMD tier boundary -- R1@32VGPR ran 58% occ / 80% VALUBusy;
// R2-R8 @72-84 all stuck at 25% occ / ~50% busy, latency-bound). Diet:
// single fv buffer loaded at phase start (h-stage covers latency), b2 read
// from LDS at epilogue, x reloaded per phase (L1-hot), row0 forced scalar.
// NO __launch_bounds__ pressure (R6/R7: forced bounds => 350-490MB spill).
__global__ __launch_bounds__(256) void it_kernel(
    const float* __restrict__ y,
    const float* __restrict__ x,
    const float* __restrict__ f_y,
    const float* __restrict__ weights,
    const float* __restrict__ W1,   // [4][64] row-major
    const float* __restrict__ b1,   // [64]
    const float* __restrict__ W2,   // [64][16] row-major
    const float* __restrict__ b2,   // [16]
    const int*   __restrict__ nbr,  // [B][M][K] int32
    float*       __restrict__ out)  // [B][M][16]
{
    __shared__ float W1L[4][64];
    __shared__ float b1L[64];
    __shared__ float b2L[16];

    const int tid  = threadIdx.x;
    W1L[tid >> 6][tid & 63] = W1[tid];
    if (tid < 64) b1L[tid] = b1[tid];
    if (tid < 16) b2L[tid] = b2[tid];

    const int lane = tid & 63;
    const int q    = lane >> 4;    // quad 0..3
    const int nlo  = lane & 15;    // neighbor-within-half; also c for W2 A-frag
    const int row0 = __builtin_amdgcn_readfirstlane((blockIdx.x * 4 + (tid >> 6)) * 2);
    const int bbase = (row0 >> 12) * N_;   // M = 4096; both rows same batch

    // ---- dedup gather: lane g covers (row g>>5, neighbor g&31) ----
    const int r_g = lane >> 5, kk = lane & 31;
    const int raw = nbr[(size_t)(row0 + r_g) * K_ + kk];
    const int vld = raw >= 0;
    const int bn_g = bbase + (vld ? raw : 0);
    const float2 yvg = *(const float2*)(y + (size_t)bn_g * 2);
    const float  wg  = vld ? weights[bn_g] : 0.0f;

    // ---- W2 A-fragment: lane holds A[m=c=nlo][k=q*8+jj] = W2[j][nlo], bf16 ----
    short8 w2f[2];
    #pragma unroll
    for (int ch = 0; ch < 2; ++ch)
        #pragma unroll
        for (int jj = 0; jj < 8; ++jj)
            w2f[ch][jj] = f2bf(W2[(ch*32 + q*8 + jj) * DOUT_ + nlo]);

    __syncthreads();   // W1L/b1L/b2L visible to all 4 waves

    float partial[4] = {0.f, 0.f, 0.f, 0.f};
    #pragma unroll
    for (int ph = 0; ph < 4; ++ph) {
        const int it = ph >> 1, h = ph & 1;
        const int src = ((it << 5) + (h << 4) + nlo) << 2;

        // this phase's f_y gather issued first; h-stage (~350cyc) covers it
        const int bn = bpermi(src, bn_g);
        const floatx4 fv = *(const floatx4*)(f_y + (size_t)bn * 16 + q * 4);

        // redistribute this phase's y / weight to (q,nlo) layout
        f32x2 yv;
        yv[0] = bpermf(src, yvg.x);
        yv[1] = bpermf(src, yvg.y);
        const float s = bpermf(src, wg);
        const float2 xv = *(const float2*)(x + (size_t)(row0 + it) * 2);  // L1-hot

        short8 hf[2];
        #pragma unroll
        for (int ch = 0; ch < 2; ++ch) {
            #pragma unroll
            for (int p = 0; p < 4; ++p) {
                const int j = ch*32 + q*8 + 2*p;
                f32x2 hin = *(const f32x2*)&b1L[j];
                hin = __builtin_elementwise_fma(splat2(yv[0]), *(const f32x2*)&W1L[0][j], hin);
                hin = __builtin_elementwise_fma(splat2(yv[1]), *(const f32x2*)&W1L[1][j], hin);
                hin = __builtin_elementwise_fma(splat2(xv.x),  *(const f32x2*)&W1L[2][j], hin);
                hin = __builtin_elementwise_fma(splat2(xv.y),  *(const f32x2*)&W1L[3][j], hin);
                const f32x2 g = gelu2(hin);
                hf[ch][2*p]     = f2bf(g[0]);
                hf[ch][2*p + 1] = f2bf(g[1]);
            }
        }
        floatx4 acc = *(const floatx4*)&b2L[q*4];   // broadcast LDS read
        acc = __builtin_amdgcn_mfma_f32_16x16x32_bf16(w2f[0], hf[0], acc, 0, 0, 0);
        acc = __builtin_amdgcn_mfma_f32_16x16x32_bf16(w2f[1], hf[1], acc, 0, 0, 0);
        #pragma unroll
        for (int r4 = 0; r4 < 4; ++r4)
            partial[r4] = fmaf(acc[r4], fv[r4] * s, partial[r4]);

        if (h == 1) {   // finished a row: reduce over 16 neighbors, store
            #pragma unroll
            for (int r4 = 0; r4 < 4; ++r4)
                partial[r4] = row16_sum(partial[r4]);
            if (nlo == 15) {
                floatx4 o = {partial[0], partial[1], partial[2], partial[3]};
                *(floatx4*)(out + (size_t)(row0 + it) * DOUT_ + q*4) = o;
            }
            #pragma unroll
            for (int r4 = 0; r4 < 4; ++r4) partial[r4] = 0.f;
        }
    }
}

extern "C" void kernel_launch(void* const* d_in, const int* in_sizes, int n_in,
                              void* d_out, int out_size, void* d_ws, size_t ws_size,
                              hipStream_t stream) {
    const float* y   = (const float*)d_in[0];
    const float* x   = (const float*)d_in[1];
    const float* f_y = (const float*)d_in[2];
    const float* w   = (const float*)d_in[3];
    const float* W1  = (const float*)d_in[4];
    const float* b1  = (const float*)d_in[5];
    const float* W2  = (const float*)d_in[6];
    const float* b2  = (const float*)d_in[7];
    const int*   nbr = (const int*)d_in[8];
    float* out = (float*)d_out;

    // 32768 rows / (4 waves * 2 rows) = 4096 blocks
    dim3 grid(B_ * M_ / 8), block(256);
    hipLaunchKernelGGL(it_kernel, grid, block, 0, stream,
                       y, x, f_y, w, W1, b1, W2, b2, nbr, out);
}

// Round 10
// 107.294 us; speedup vs baseline: 1.0178x; 1.0178x over previous
//
#include <hip/hip_runtime.h>
#include <hip/hip_bf16.h>

#define B_    8
#define N_    9225
#define M_    4096
#define K_    32
#define HID_  64
#define DOUT_ 16
#define NWAVES 4096   // persistent waves
#define ITERS  4      // row-pairs per wave (4096*4 = 16384 pairs = 32768 rows)

typedef __attribute__((ext_vector_type(8))) short short8;
typedef __attribute__((ext_vector_type(4))) float floatx4;
typedef __attribute__((ext_vector_type(2))) float f32x2;

static __device__ __forceinline__ short f2bf(float f) {
    __hip_bfloat16 h = __float2bfloat16(f);
    return __builtin_bit_cast(short, h);
}
static __device__ __forceinline__ f32x2 splat2(float v) { return (f32x2){v, v}; }
static __device__ __forceinline__ int bpermi(int src_bytes, int v) {
    return __builtin_amdgcn_ds_bpermute(src_bytes, v);
}
static __device__ __forceinline__ float bpermf(int src_bytes, float v) {
    return __builtin_bit_cast(float,
        __builtin_amdgcn_ds_bpermute(src_bytes, __builtin_bit_cast(int, v)));
}

// Sum over each 16-lane DPP row via row_shr tree; lane (row*16+15) holds the sum.
static __device__ __forceinline__ float row16_sum(float v) {
    int t;
    t = __builtin_amdgcn_update_dpp(0, __builtin_bit_cast(int, v), 0x111, 0xF, 0xF, true);
    v += __builtin_bit_cast(float, t);
    t = __builtin_amdgcn_update_dpp(0, __builtin_bit_cast(int, v), 0x112, 0xF, 0xF, true);
    v += __builtin_bit_cast(float, t);
    t = __builtin_amdgcn_update_dpp(0, __builtin_bit_cast(int, v), 0x114, 0xF, 0xF, true);
    v += __builtin_bit_cast(float, t);
    t = __builtin_amdgcn_update_dpp(0, __builtin_bit_cast(int, v), 0x118, 0xF, 0xF, true);
    v += __builtin_bit_cast(float, t);
    return v;
}

// gelu(x) ~ 0.5*x*(1 + tanh(z)), z = x*(0.79788456 + 0.035677408*x^2),
// tanh via Pade(5,4), clamped to [-1,1]. No v_exp. (Validated R4/R5/R8.)
static __device__ __forceinline__ f32x2 gelu2(f32x2 x) {
    const f32x2 xsq = x * x;
    const f32x2 t   = __builtin_elementwise_fma(xsq, splat2(0.035677408f), splat2(0.79788456f));
    const f32x2 z   = x * t;
    const f32x2 u   = z * z;
    const f32x2 a   = u + splat2(105.0f);
    const f32x2 nin = __builtin_elementwise_fma(u, a, splat2(945.0f));
    const f32x2 num = z * nin;
    const f32x2 bq  = __builtin_elementwise_fma(u, splat2(15.0f), splat2(420.0f));
    const f32x2 den = __builtin_elementwise_fma(u, bq, splat2(945.0f));
    const f32x2 r   = { __builtin_amdgcn_rcpf(den[0]), __builtin_amdgcn_rcpf(den[1]) };
    f32x2 th = num * r;
    th = __builtin_elementwise_min(__builtin_elementwise_max(th, splat2(-1.0f)), splat2(1.0f));
    const f32x2 hx = x * splat2(0.5f);
    return __builtin_elementwise_fma(hx, th, hx);
}

// PERSISTENT-WAVE version of the validated R8 structure. R2-R9 were pinned at
// ~41us by ~3000cyc/wave of un-overlapped latency: short-lived waves pay a
// ~1300cyc serial gather head (cold nbr -> dependent y/w -> bperm) plus
// per-block setup, and slot refill bubbles held time-avg residency at
// 2 waves/SIMD. Here each wave owns ITERS row-pairs (strided NWAVES for a
// contiguous GPU-wide nbr sweep): next pair's nbr+x issue at iteration start
// (~1400cyc cover), dependent y/w mid-iteration (~700cyc cover); W1-staging /
// w2f setup amortized 4x. Grid = 1024 blocks = 4/CU: all slots filled once,
// no churn. Compute per phase identical to R8 (LDS W1, MFMA W2, DPP reduce).
__global__ __launch_bounds__(256) void it_kernel(
    const float* __restrict__ y,
    const float* __restrict__ x,
    const float* __restrict__ f_y,
    const float* __restrict__ weights,
    const float* __restrict__ W1,   // [4][64] row-major
    const float* __restrict__ b1,   // [64]
    const float* __restrict__ W2,   // [64][16] row-major
    const float* __restrict__ b2,   // [16]
    const int*   __restrict__ nbr,  // [B][M][K] int32
    float*       __restrict__ out)  // [B][M][16]
{
    __shared__ float W1L[4][64];
    __shared__ float b1L[64];
    __shared__ float b2L[16];

    const int tid  = threadIdx.x;
    W1L[tid >> 6][tid & 63] = W1[tid];
    if (tid < 64) b1L[tid] = b1[tid];
    if (tid < 16) b2L[tid] = b2[tid];

    const int lane = tid & 63;
    const int q    = lane >> 4;    // quad 0..3
    const int nlo  = lane & 15;    // neighbor-within-half; also c for W2 A-frag
    const int r_g  = lane >> 5, kk = lane & 31;
    const int wid  = __builtin_amdgcn_readfirstlane(blockIdx.x * 4 + (tid >> 6));

    // ---- W2 A-fragment: lane holds A[m=c=nlo][k=q*8+jj] = W2[j][nlo], bf16 ----
    short8 w2f[2];
    #pragma unroll
    for (int ch = 0; ch < 2; ++ch)
        #pragma unroll
        for (int jj = 0; jj < 8; ++jj)
            w2f[ch][jj] = f2bf(W2[(ch*32 + q*8 + jj) * DOUT_ + nlo]);

    // ---- prologue: gathers for pair 0 ----
    int row0 = wid * 2;
    {
    }
    int raw = nbr[(size_t)(row0 + r_g) * K_ + kk];
    float2 xv0 = *(const float2*)(x + (size_t)row0 * 2);
    float2 xv1 = *(const float2*)(x + (size_t)row0 * 2 + 2);
    int   vld  = raw >= 0;
    int   bn_g = (row0 >> 12) * N_ + (vld ? raw : 0);
    float2 yvg = *(const float2*)(y + (size_t)bn_g * 2);
    float  wg  = vld ? weights[bn_g] : 0.0f;

    __syncthreads();   // W1L/b1L/b2L visible to all 4 waves

    for (int itn = 0; itn < ITERS; ++itn) {
        const int row0n = row0 + NWAVES * 2;   // next pair's base row

        // ---- prefetch next pair's nbr + x at iteration start ----
        int raw_n = 0; float2 xv0_n = {0,0}, xv1_n = {0,0};
        if (itn + 1 < ITERS) {
            raw_n  = nbr[(size_t)(row0n + r_g) * K_ + kk];
            xv0_n  = *(const float2*)(x + (size_t)row0n * 2);
            xv1_n  = *(const float2*)(x + (size_t)row0n * 2 + 2);
        }
        int bn_gn = 0; float2 yvg_n = {0,0}; float wg_n = 0.0f;

        float partial[4] = {0.f, 0.f, 0.f, 0.f};
        #pragma unroll
        for (int ph = 0; ph < 4; ++ph) {
            const int it = ph >> 1, h = ph & 1;
            const int src = ((it << 5) + (h << 4) + nlo) << 2;

            // this phase's f_y gather issued first; h-stage covers it
            const int bn = bpermi(src, bn_g);
            const floatx4 fv = *(const floatx4*)(f_y + (size_t)bn * 16 + q * 4);

            // redistribute this phase's y / weight to (q,nlo) layout
            f32x2 yv;
            yv[0] = bpermf(src, yvg.x);
            yv[1] = bpermf(src, yvg.y);
            const float s = bpermf(src, wg);
            const float2 xv = it ? xv1 : xv0;

            short8 hf[2];
            #pragma unroll
            for (int ch = 0; ch < 2; ++ch) {
                #pragma unroll
                for (int p = 0; p < 4; ++p) {
                    const int j = ch*32 + q*8 + 2*p;
                    f32x2 hin = *(const f32x2*)&b1L[j];
                    hin = __builtin_elementwise_fma(splat2(yv[0]), *(const f32x2*)&W1L[0][j], hin);
                    hin = __builtin_elementwise_fma(splat2(yv[1]), *(const f32x2*)&W1L[1][j], hin);
                    hin = __builtin_elementwise_fma(splat2(xv.x),  *(const f32x2*)&W1L[2][j], hin);
                    hin = __builtin_elementwise_fma(splat2(xv.y),  *(const f32x2*)&W1L[3][j], hin);
                    const f32x2 g = gelu2(hin);
                    hf[ch][2*p]     = f2bf(g[0]);
                    hf[ch][2*p + 1] = f2bf(g[1]);
                }
            }
            floatx4 acc = *(const floatx4*)&b2L[q*4];   // broadcast LDS read
            acc = __builtin_amdgcn_mfma_f32_16x16x32_bf16(w2f[0], hf[0], acc, 0, 0, 0);
            acc = __builtin_amdgcn_mfma_f32_16x16x32_bf16(w2f[1], hf[1], acc, 0, 0, 0);
            #pragma unroll
            for (int r4 = 0; r4 < 4; ++r4)
                partial[r4] = fmaf(acc[r4], fv[r4] * s, partial[r4]);

            if (h == 1) {   // finished a row: reduce over 16 neighbors, store
                #pragma unroll
                for (int r4 = 0; r4 < 4; ++r4)
                    partial[r4] = row16_sum(partial[r4]);
                if (nlo == 15) {
                    floatx4 o = {partial[0], partial[1], partial[2], partial[3]};
                    *(floatx4*)(out + (size_t)(row0 + it) * DOUT_ + q*4) = o;
                }
                #pragma unroll
                for (int r4 = 0; r4 < 4; ++r4) partial[r4] = 0.f;
            }

            // ---- mid-iteration: issue next pair's dependent y/w gathers ----
            if (ph == 1 && itn + 1 < ITERS) {
                const int vld_n = raw_n >= 0;
                bn_gn = (row0n >> 12) * N_ + (vld_n ? raw_n : 0);
                yvg_n = *(const float2*)(y + (size_t)bn_gn * 2);
                wg_n  = vld_n ? weights[bn_gn] : 0.0f;
            }
        }

        // ---- rotate pipeline state ----
        row0 = row0n;
        bn_g = bn_gn; yvg = yvg_n; wg = wg_n;
        xv0 = xv0_n; xv1 = xv1_n;
    }
}

extern "C" void kernel_launch(void* const* d_in, const int* in_sizes, int n_in,
                              void* d_out, int out_size, void* d_ws, size_t ws_size,
                              hipStream_t stream) {
    const float* y   = (const float*)d_in[0];
    const float* x   = (const float*)d_in[1];
    const float* f_y = (const float*)d_in[2];
    const float* w   = (const float*)d_in[3];
    const float* W1  = (const float*)d_in[4];
    const float* b1  = (const float*)d_in[5];
    const float* W2  = (const float*)d_in[6];
    const float* b2  = (const float*)d_in[7];
    const int*   nbr = (const int*)d_in[8];
    float* out = (float*)d_out;

    // 4096 persistent waves = 1024 blocks (4 blocks/CU, all slots filled once)
    dim3 grid(NWAVES / 4), block(256);
    hipLaunchKernelGGL(it_kernel, grid, block, 0, stream,
                       y, x, f_y, w, W1, b1, W2, b2, nbr, out);
}